// Round 1
// baseline (1978.555 us; speedup 1.0000x reference)
//
#include <hip/hip_runtime.h>
#include <cstdint>
#include <cstddef>

#define NLVL 4
#define NF 8
#define TSIZE (1u << 19)
#define NH 64
#define NOUT 128

// sin(x) for x in radians: v_sin takes revolutions, reduce with v_fract
__device__ __forceinline__ float fsin_rad(float x) {
    return __builtin_amdgcn_sinf(__builtin_amdgcn_fractf(x * 0.15915494309189535f));
}
// sin(2*pi*r)
__device__ __forceinline__ float fsin_rev(float r) {
    return __builtin_amdgcn_sinf(__builtin_amdgcn_fractf(r));
}

__global__ __launch_bounds__(256, 2)
void ffb_fused(const float* __restrict__ in_pos,
               const float* __restrict__ table,
               const float* __restrict__ ffn,
               const float* __restrict__ W0,
               const float* __restrict__ b0,
               const float* __restrict__ Ws,
               const float* __restrict__ bs,
               const float* __restrict__ Wout,
               const float* __restrict__ bout,
               float* __restrict__ out)
{
    // x activations: [feature][thread] -> lane-contiguous, conflict-free.
    // Each thread owns column tid exclusively: no __syncthreads needed.
    __shared__ float xs[NH][256];

    const int tid = threadIdx.x;
    const int gid = blockIdx.x * 256 + tid;

    const float px = in_pos[3 * gid + 0];
    const float py = in_pos[3 * gid + 1];
    const float pz = in_pos[3 * gid + 2];

    // ---- layer 0: x = sin(30*(pos @ W0 + b0))  (BOUND=1 so SIREN input = in_pos)
    #pragma unroll
    for (int j = 0; j < NH; ++j) {
        float a = b0[j];
        a = fmaf(px, W0[j], a);
        a = fmaf(py, W0[NH + j], a);
        a = fmaf(pz, W0[2 * NH + j], a);
        xs[j][tid] = fsin_rad(30.f * a);
    }

    float acc_out[NOUT];
    #pragma unroll
    for (int j = 0; j < NOUT; ++j) acc_out[j] = 0.f;

    const float q01x = (px + 1.f) * 0.5f;
    const float q01y = (py + 1.f) * 0.5f;
    const float q01z = (pz + 1.f) * 0.5f;

    const uint32_t P1 = 2654435761u, P2 = 805459861u;

    #pragma unroll 1
    for (int l = 0; l < NLVL; ++l) {
        // ---- hash-grid gather + trilinear interp -> g[8]
        const float res = (float)(16 << l);
        const float gxp = q01x * res, gyp = q01y * res, gzp = q01z * res;
        const float fx0 = floorf(gxp), fy0 = floorf(gyp), fz0 = floorf(gzp);
        const float fx = gxp - fx0, fy = gyp - fy0, fz = gzp - fz0;
        const uint32_t ux = (uint32_t)fx0, uy = (uint32_t)fy0, uz = (uint32_t)fz0;
        const uint32_t hx0 = ux, hx1 = ux + 1u;
        const uint32_t hy0 = uy * P1, hy1 = hy0 + P1;
        const uint32_t hz0 = uz * P2, hz1 = hz0 + P2;
        const float* tl = table + (size_t)l * (size_t)TSIZE * NF;

        float g[NF];
        #pragma unroll
        for (int q = 0; q < NF; ++q) g[q] = 0.f;

        #pragma unroll
        for (int c = 0; c < 8; ++c) {   // corner bits: [x=bit2, y=bit1, z=bit0]
            const uint32_t h = (((c & 4) ? hx1 : hx0) ^ ((c & 2) ? hy1 : hy0)
                                ^ ((c & 1) ? hz1 : hz0)) & (TSIZE - 1u);
            const float w = ((c & 4) ? fx : 1.f - fx)
                          * ((c & 2) ? fy : 1.f - fy)
                          * ((c & 1) ? fz : 1.f - fz);
            const float4* fp = (const float4*)(tl + (size_t)h * NF);
            const float4 va = fp[0];
            const float4 vb = fp[1];
            g[0] = fmaf(w, va.x, g[0]); g[1] = fmaf(w, va.y, g[1]);
            g[2] = fmaf(w, va.z, g[2]); g[3] = fmaf(w, va.w, g[3]);
            g[4] = fmaf(w, vb.x, g[4]); g[5] = fmaf(w, vb.y, g[5]);
            g[6] = fmaf(w, vb.z, g[6]); g[7] = fmaf(w, vb.w, g[7]);
        }

        const float* Wl = Ws  + (size_t)l * NH * NH;
        const float* bl = bs  + (size_t)l * NH;
        const float* Fl = ffn + (size_t)l * NF * NH;

        // ---- phase B: xn = sin(30*(x@Ws + bs)) + sin(2pi*(g@ffn))
        float xn[NH];
        #pragma unroll
        for (int jc = 0; jc < NH; jc += 8) {
            float aw[8];
            #pragma unroll
            for (int u = 0; u < 8; ++u) aw[u] = bl[jc + u];
            #pragma unroll 4
            for (int k = 0; k < NH; ++k) {
                const float xk = xs[k][tid];
                #pragma unroll
                for (int u = 0; u < 8; ++u)
                    aw[u] = fmaf(xk, Wl[k * NH + jc + u], aw[u]);
            }
            float ae[8];
            #pragma unroll
            for (int u = 0; u < 8; ++u) ae[u] = 0.f;
            #pragma unroll
            for (int f = 0; f < NF; ++f) {
                #pragma unroll
                for (int u = 0; u < 8; ++u)
                    ae[u] = fmaf(g[f], Fl[f * NH + jc + u], ae[u]);
            }
            #pragma unroll
            for (int u = 0; u < 8; ++u)
                xn[jc + u] = fsin_rad(30.f * aw[u]) + fsin_rev(ae[u]);
        }
        // commit new x (thread-private column; no barrier needed)
        #pragma unroll
        for (int j = 0; j < NH; ++j) xs[j][tid] = xn[j];

        // ---- phase C: out += sin(30*(x@Wout + bout))
        const float* Wo = Wout + (size_t)l * NH * NOUT;
        const float* bo = bout + (size_t)l * NOUT;
        #pragma unroll
        for (int jc = 0; jc < NOUT; jc += 16) {
            float ao[16];
            #pragma unroll
            for (int u = 0; u < 16; ++u) ao[u] = bo[jc + u];
            #pragma unroll 4
            for (int k = 0; k < NH; ++k) {
                const float xk = xs[k][tid];
                #pragma unroll
                for (int u = 0; u < 16; ++u)
                    ao[u] = fmaf(xk, Wo[k * NOUT + jc + u], ao[u]);
            }
            #pragma unroll
            for (int u = 0; u < 16; ++u)
                acc_out[jc + u] += fsin_rad(30.f * ao[u]);
        }
    }

    float4* op = (float4*)(out + (size_t)gid * NOUT);
    #pragma unroll
    for (int q = 0; q < NOUT / 4; ++q) {
        op[q] = make_float4(acc_out[4 * q + 0], acc_out[4 * q + 1],
                            acc_out[4 * q + 2], acc_out[4 * q + 3]);
    }
}

extern "C" void kernel_launch(void* const* d_in, const int* in_sizes, int n_in,
                              void* d_out, int out_size, void* d_ws, size_t ws_size,
                              hipStream_t stream) {
    const float* in_pos = (const float*)d_in[0];
    const float* table  = (const float*)d_in[1];
    const float* ffn    = (const float*)d_in[2];
    const float* W0     = (const float*)d_in[3];
    const float* b0     = (const float*)d_in[4];
    const float* Ws     = (const float*)d_in[5];
    const float* bs     = (const float*)d_in[6];
    const float* Wout   = (const float*)d_in[7];
    const float* bout   = (const float*)d_in[8];
    float* out = (float*)d_out;

    const int n = in_sizes[0] / 3;          // 524288 points
    ffb_fused<<<dim3(n / 256), dim3(256), 0, stream>>>(
        in_pos, table, ffn, W0, b0, Ws, bs, Wout, bout, out);
}

// Round 2
// 346.767 us; speedup vs baseline: 5.7057x; 5.7057x over previous
//
#include <hip/hip_runtime.h>
#include <cstdint>
#include <cstddef>

#define NLVL 4
#define TSIZE (1u << 19)
#define NH 64
#define NOUT 128
#define MBLK 128

typedef _Float16 f16x8 __attribute__((ext_vector_type(8)));
typedef float f32x4 __attribute__((ext_vector_type(4)));
typedef unsigned short u16x8 __attribute__((ext_vector_type(8)));

__device__ __forceinline__ float fsin_rad(float x) {
    return __builtin_amdgcn_sinf(__builtin_amdgcn_fractf(x * 0.15915494309189535f));
}
__device__ __forceinline__ float fsin_rev(float r) {
    return __builtin_amdgcn_sinf(__builtin_amdgcn_fractf(r));
}
__device__ __forceinline__ unsigned short h2u(_Float16 h) {
    return __builtin_bit_cast(unsigned short, h);
}

// ---- prep kernel: transpose weights to [col][k] layout, f16, into d_ws ----
// ws layout (f16 elems): WsT 0..16384, WoutT 16384..49152, ffnT 49152..51200
__global__ void prep_weights(const float* __restrict__ Ws,
                             const float* __restrict__ Wout,
                             const float* __restrict__ ffn,
                             _Float16* __restrict__ ws)
{
    int i = blockIdx.x * 256 + threadIdx.x;
    _Float16* WsT = ws;            // [4][64 col][64 k]
    _Float16* WoT = ws + 16384;    // [4][128 col][64 k]
    _Float16* FfT = ws + 49152;    // [4][64 col][8 k]
    if (i < 16384) {
        int l = i >> 12, r = i & 4095, k = r >> 6, c = r & 63;
        WsT[l * 4096 + c * 64 + k] = (_Float16)Ws[i];
    } else if (i < 49152) {
        int j = i - 16384;
        int l = j >> 13, r = j & 8191, k = r >> 7, c = r & 127;
        WoT[l * 8192 + c * 64 + k] = (_Float16)Wout[j];
    } else if (i < 51200) {
        int j = i - 49152;
        int l = j >> 9, r = j & 511, k = r >> 6, c = r & 63;
        FfT[l * 512 + c * 8 + k] = (_Float16)ffn[j];
    }
}

__global__ __launch_bounds__(256, 2)
void ffb_main(const float* __restrict__ in_pos,
              const float* __restrict__ table,
              const float* __restrict__ W0,
              const float* __restrict__ b0,
              const float* __restrict__ bs,
              const float* __restrict__ bout,
              const _Float16* __restrict__ ws,
              float* __restrict__ out)
{
    // X planes: [128 rows][64 cols] f16, XOR-swizzled: idx = row*64 + (col ^ ((row&7)<<3))
    __shared__ __align__(16) unsigned short Xh[MBLK * NH];
    __shared__ __align__(16) unsigned short Xl[MBLK * NH];
    __shared__ __align__(16) unsigned short gS[NLVL][MBLK][8];   // g scaled by 4096, f16

    const int tid = threadIdx.x;
    const int pbase = blockIdx.x * MBLK;

    // ---------- stage 1: hash-grid gather (2 levels per thread) + layer0 ----------
    {
        const int p = tid & 127;
        const float px = in_pos[3 * (pbase + p) + 0];
        const float py = in_pos[3 * (pbase + p) + 1];
        const float pz = in_pos[3 * (pbase + p) + 2];
        const float qx = (px + 1.f) * 0.5f, qy = (py + 1.f) * 0.5f, qz = (pz + 1.f) * 0.5f;
        const uint32_t P1 = 2654435761u, P2 = 805459861u;
        const int lv0 = (tid >> 7) * 2;
        #pragma unroll 1
        for (int t = 0; t < 2; ++t) {
            const int lv = lv0 + t;
            const float res = (float)(16 << lv);
            float gx = qx * res, gy = qy * res, gz = qz * res;
            float fx0 = floorf(gx), fy0 = floorf(gy), fz0 = floorf(gz);
            float fx = gx - fx0, fy = gy - fy0, fz = gz - fz0;
            uint32_t ux = (uint32_t)fx0, uy = (uint32_t)fy0, uz = (uint32_t)fz0;
            uint32_t hx0 = ux, hx1 = ux + 1u;
            uint32_t hy0 = uy * P1, hy1 = hy0 + P1;
            uint32_t hz0 = uz * P2, hz1 = hz0 + P2;
            const float* tl = table + (size_t)lv * TSIZE * 8;
            float g[8];
            #pragma unroll
            for (int q = 0; q < 8; ++q) g[q] = 0.f;
            #pragma unroll
            for (int c = 0; c < 8; ++c) {
                uint32_t h = (((c & 4) ? hx1 : hx0) ^ ((c & 2) ? hy1 : hy0)
                              ^ ((c & 1) ? hz1 : hz0)) & (TSIZE - 1u);
                float w = ((c & 4) ? fx : 1.f - fx) * ((c & 2) ? fy : 1.f - fy)
                        * ((c & 1) ? fz : 1.f - fz);
                const float4* fp = (const float4*)(tl + (size_t)h * 8);
                float4 va = fp[0], vb = fp[1];
                g[0] = fmaf(w, va.x, g[0]); g[1] = fmaf(w, va.y, g[1]);
                g[2] = fmaf(w, va.z, g[2]); g[3] = fmaf(w, va.w, g[3]);
                g[4] = fmaf(w, vb.x, g[4]); g[5] = fmaf(w, vb.y, g[5]);
                g[6] = fmaf(w, vb.z, g[6]); g[7] = fmaf(w, vb.w, g[7]);
            }
            u16x8 gv;
            #pragma unroll
            for (int q = 0; q < 8; ++q)
                gv[q] = h2u((_Float16)(g[q] * 4096.f));   // scale: avoid f16 denormal flush
            *(u16x8*)&gS[lv][p][0] = gv;
        }
        // layer0: x0 = sin(30*(pos@W0 + b0)); this thread does 32 cols of point p
        const int ch = (tid >> 7) * 32;
        #pragma unroll 4
        for (int c = ch; c < ch + 32; c += 2) {
            float a0 = b0[c]     + px * W0[c]       + py * W0[64 + c]  + pz * W0[128 + c];
            float a1 = b0[c + 1] + px * W0[c + 1]   + py * W0[65 + c]  + pz * W0[129 + c];
            float x0 = fsin_rad(30.f * a0);
            float x1 = fsin_rad(30.f * a1);
            _Float16 h0 = (_Float16)x0, h1 = (_Float16)x1;
            _Float16 l0 = (_Float16)(x0 - (float)h0), l1 = (_Float16)(x1 - (float)h1);
            int idx = p * 64 + (c ^ ((p & 7) << 3));
            *(unsigned int*)&Xh[idx] = (unsigned int)h2u(h0) | ((unsigned int)h2u(h1) << 16);
            *(unsigned int*)&Xl[idx] = (unsigned int)h2u(l0) | ((unsigned int)h2u(l1) << 16);
        }
    }
    __syncthreads();
    // After this barrier: wave wv exclusively owns X-plane rows [wv*32, wv*32+32). No more barriers.

    const int lane = tid & 63;
    const int wv = tid >> 6;
    const int r15 = lane & 15;
    const int hi4 = lane >> 4;
    const char* Xhb = (const char*)Xh;
    const char* Xlb = (const char*)Xl;

    // A-fragments (held across phases): lane -> row = base + (lane&15), k = kb*32 + (lane>>4)*8 + j
    f16x8 Axh[2][2], Axl[2][2];
    auto loadA = [&]() {
        #pragma unroll
        for (int rt = 0; rt < 2; ++rt)
            #pragma unroll
            for (int kb = 0; kb < 2; ++kb) {
                int row = wv * 32 + rt * 16 + r15;
                int off = row * 128 + ((kb * 64 + hi4 * 16) ^ ((row & 7) << 4));
                Axh[rt][kb] = *(const f16x8*)(Xhb + off);
                Axl[rt][kb] = *(const f16x8*)(Xlb + off);
            }
    };
    loadA();

    float acc[2][8][4];
    #pragma unroll
    for (int rt = 0; rt < 2; ++rt)
        #pragma unroll
        for (int ct = 0; ct < 8; ++ct)
            #pragma unroll
            for (int r = 0; r < 4; ++r) acc[rt][ct][r] = 0.f;

    const _Float16* WsT = ws;
    const _Float16* WoT = ws + 16384;
    const _Float16* FfT = ws + 49152;

    #pragma unroll 1
    for (int lvl = 0; lvl < NLVL; ++lvl) {
        // g A-frags: only lanes 0-15 carry k<8; rest zero
        f16x8 Ag[2];
        #pragma unroll
        for (int rt = 0; rt < 2; ++rt) {
            f16x8 z;
            #pragma unroll
            for (int q = 0; q < 8; ++q) z[q] = (_Float16)0.f;
            if (lane < 16)
                z = *(const f16x8*)&gS[lvl][wv * 32 + rt * 16 + lane][0];
            Ag[rt] = z;
        }

        // ---- phase B: xn = sin(30*(X@Ws + bs)) + sin(2pi*(g@ffn)) ----
        #pragma unroll
        for (int ct = 0; ct < 4; ++ct) {
            const _Float16* bp = WsT + lvl * 4096 + (ct * 16 + r15) * 64 + hi4 * 8;
            f16x8 B0 = *(const f16x8*)bp;          // kb = 0
            f16x8 B1 = *(const f16x8*)(bp + 32);   // kb = 1
            f16x8 Bf;
            #pragma unroll
            for (int q = 0; q < 8; ++q) Bf[q] = (_Float16)0.f;
            if (lane < 16)
                Bf = *(const f16x8*)(FfT + lvl * 512 + (ct * 16 + r15) * 8);
            float bsv = bs[lvl * 64 + ct * 16 + r15];
            #pragma unroll
            for (int rt = 0; rt < 2; ++rt) {
                f32x4 c1 = {0.f, 0.f, 0.f, 0.f};
                c1 = __builtin_amdgcn_mfma_f32_16x16x32_f16(Axh[rt][0], B0, c1, 0, 0, 0);
                c1 = __builtin_amdgcn_mfma_f32_16x16x32_f16(Axl[rt][0], B0, c1, 0, 0, 0);
                c1 = __builtin_amdgcn_mfma_f32_16x16x32_f16(Axh[rt][1], B1, c1, 0, 0, 0);
                c1 = __builtin_amdgcn_mfma_f32_16x16x32_f16(Axl[rt][1], B1, c1, 0, 0, 0);
                f32x4 c2 = {0.f, 0.f, 0.f, 0.f};
                c2 = __builtin_amdgcn_mfma_f32_16x16x32_f16(Ag[rt], Bf, c2, 0, 0, 0);
                #pragma unroll
                for (int r = 0; r < 4; ++r) {
                    int row = wv * 32 + rt * 16 + hi4 * 4 + r;
                    int col = ct * 16 + r15;
                    float xn = fsin_rad(30.f * (c1[r] + bsv))
                             + fsin_rev(c2[r] * 0.000244140625f);  // /4096
                    _Float16 h = (_Float16)xn;
                    _Float16 lo = (_Float16)(xn - (float)h);
                    int idx = row * 64 + (col ^ ((row & 7) << 3));
                    Xh[idx] = h2u(h);
                    Xl[idx] = h2u(lo);
                }
            }
        }
        loadA();   // new x -> A-frags (also reused by next level's phase B)

        // ---- phase C: out += sin(30*(x@Wout + bout)) ----
        #pragma unroll
        for (int ct = 0; ct < 8; ++ct) {
            const _Float16* bp = WoT + lvl * 8192 + (ct * 16 + r15) * 64 + hi4 * 8;
            f16x8 B0 = *(const f16x8*)bp;
            f16x8 B1 = *(const f16x8*)(bp + 32);
            float bov = bout[lvl * 128 + ct * 16 + r15];
            #pragma unroll
            for (int rt = 0; rt < 2; ++rt) {
                f32x4 c = {0.f, 0.f, 0.f, 0.f};
                c = __builtin_amdgcn_mfma_f32_16x16x32_f16(Axh[rt][0], B0, c, 0, 0, 0);
                c = __builtin_amdgcn_mfma_f32_16x16x32_f16(Axl[rt][0], B0, c, 0, 0, 0);
                c = __builtin_amdgcn_mfma_f32_16x16x32_f16(Axh[rt][1], B1, c, 0, 0, 0);
                c = __builtin_amdgcn_mfma_f32_16x16x32_f16(Axl[rt][1], B1, c, 0, 0, 0);
                #pragma unroll
                for (int r = 0; r < 4; ++r)
                    acc[rt][ct][r] += fsin_rad(30.f * (c[r] + bov));
            }
        }
    }

    // ---- store: ct innermost so the 64B half-lines of one row merge in L2 ----
    #pragma unroll
    for (int rt = 0; rt < 2; ++rt)
        #pragma unroll
        for (int r = 0; r < 4; ++r)
            #pragma unroll
            for (int ct = 0; ct < 8; ++ct) {
                int row = pbase + wv * 32 + rt * 16 + hi4 * 4 + r;
                out[(size_t)row * 128 + ct * 16 + r15] = acc[rt][ct][r];
            }
}

extern "C" void kernel_launch(void* const* d_in, const int* in_sizes, int n_in,
                              void* d_out, int out_size, void* d_ws, size_t ws_size,
                              hipStream_t stream) {
    const float* in_pos = (const float*)d_in[0];
    const float* table  = (const float*)d_in[1];
    const float* ffn    = (const float*)d_in[2];
    const float* W0     = (const float*)d_in[3];
    const float* b0     = (const float*)d_in[4];
    const float* Ws     = (const float*)d_in[5];
    const float* bs     = (const float*)d_in[6];
    const float* Wout   = (const float*)d_in[7];
    const float* bout   = (const float*)d_in[8];
    float* out = (float*)d_out;
    _Float16* ws = (_Float16*)d_ws;   // needs 102,400 B

    prep_weights<<<dim3(200), dim3(256), 0, stream>>>(Ws, Wout, ffn, ws);

    const int n = in_sizes[0] / 3;    // 524288
    ffb_main<<<dim3(n / MBLK), dim3(256), 0, stream>>>(
        in_pos, table, W0, b0, bs, bout, ws, out);
}